// Round 7
// baseline (1882.930 us; speedup 1.0000x reference)
//
#include <hip/hip_runtime.h>
#include <hip/hip_bf16.h>
#include <hip/hip_cooperative_groups.h>

#define T_TOK 2048
#define DIMS  1024
#define HID   4096
#define NE    8
#define BM 128
#define BN 128
#define BK 64

namespace cg = cooperative_groups;

typedef __bf16 bf16x8 __attribute__((ext_vector_type(8)));
typedef float  f32x4  __attribute__((ext_vector_type(4)));

__device__ __forceinline__ unsigned short f2bf(float f) {
  unsigned u = __float_as_uint(f);
  u += 0x7FFFu + ((u >> 16) & 1u);
  return (unsigned short)(u >> 16);
}
__device__ __forceinline__ float bf2f(unsigned short s) {
  return __uint_as_float(((unsigned)s) << 16);
}

__device__ __forceinline__ void g2l16(const void* g, void* l) {
  __builtin_amdgcn_global_load_lds((const __attribute__((address_space(1))) void*)g,
                                   (__attribute__((address_space(3))) void*)l,
                                   16, 0, 0);
}

// fp32 [r][c] tile (128x128) -> bf16 transposed [c][r], via swizzled LDS. 256 thr.
__device__ __forceinline__ void transcode_tile(const float* __restrict__ src,
    unsigned short* __restrict__ dst, int src_ld, int dst_ld, int r0, int c0,
    unsigned short* lds, int tid) {
  int rbase = tid >> 5;
  int c4l = (tid & 31) * 4;
#pragma unroll 4
  for (int it = 0; it < 16; it++) {
    int r = rbase + it * 8;
    float4 v = *(const float4*)(src + (size_t)(r0 + r) * src_ld + c0 + c4l);
    unsigned short b[4];
    b[0] = f2bf(v.x); b[1] = f2bf(v.y); b[2] = f2bf(v.z); b[3] = f2bf(v.w);
#pragma unroll
    for (int j = 0; j < 4; j++) {
      int c = c4l + j;
      int chunk = it ^ ((c >> 2) & 15);
      lds[c * 128 + chunk * 8 + rbase] = b[j];
    }
  }
  __syncthreads();
  int ck = tid & 15;
  int cb = tid >> 4;
#pragma unroll 4
  for (int it = 0; it < 8; it++) {
    int c = cb + it * 16;
    int chunk = ck ^ ((c >> 2) & 15);
    uint4 v = *(const uint4*)(&lds[c * 128 + chunk * 8]);
    *(uint4*)(dst + (size_t)(c0 + c) * dst_ld + r0 + ck * 8) = v;
  }
}

// ---------------- phase bodies (r0-proven code, persistent-callable) ---------

__device__ __forceinline__ void route_body(int t, int lane,
    const float* __restrict__ u, const float* __restrict__ cent,
    const float* __restrict__ sbias, int* __restrict__ topk_idx,
    float* __restrict__ topk_val, unsigned short* __restrict__ ub) {
  const float* ur = u + (size_t)t * DIMS;
  float p[NE];
#pragma unroll
  for (int n = 0; n < NE; n++) p[n] = 0.f;
#pragma unroll
  for (int ch = 0; ch < 4; ch++) {
    int d = ch * 256 + lane * 4;
    float4 uv = *(const float4*)(ur + d);
    ushort4 o4;
    o4.x = f2bf(uv.x); o4.y = f2bf(uv.y); o4.z = f2bf(uv.z); o4.w = f2bf(uv.w);
    *(ushort4*)(ub + (size_t)t * DIMS + d) = o4;
#pragma unroll
    for (int n = 0; n < NE; n++) {
      float4 cv = *(const float4*)(cent + n * DIMS + d);
      p[n] += uv.x * cv.x + uv.y * cv.y + uv.z * cv.z + uv.w * cv.w;
    }
  }
#pragma unroll
  for (int n = 0; n < NE; n++) {
#pragma unroll
    for (int o = 32; o > 0; o >>= 1) p[n] += __shfl_xor(p[n], o);
  }
  if (lane == 0) {
    float g[NE];
    float m = -1e30f;
#pragma unroll
    for (int n = 0; n < NE; n++) { g[n] = p[n] + sbias[n]; m = fmaxf(m, g[n]); }
    float sum = 0.f;
#pragma unroll
    for (int n = 0; n < NE; n++) { g[n] = expf(g[n] - m); sum += g[n]; }
    float inv = 1.f / sum;
#pragma unroll
    for (int n = 0; n < NE; n++) g[n] *= inv;
    int i0 = 0;
#pragma unroll
    for (int n = 1; n < NE; n++) if (g[n] > g[i0]) i0 = n;
    int i1 = (i0 == 0) ? 1 : 0;
#pragma unroll
    for (int n = 0; n < NE; n++) if (n != i0 && g[n] > g[i1]) i1 = n;
    topk_idx[2 * t] = i0;     topk_idx[2 * t + 1] = i1;
    topk_val[2 * t] = g[i0];  topk_val[2 * t + 1] = g[i1];
  }
}

// scan-based finalize; needs >= 8448 bytes of LDS scratch
__device__ __forceinline__ void finalize_body(int tid, unsigned char* smemB,
    const int* __restrict__ topk_idx, int* __restrict__ cnt, int* __restrict__ offs,
    float* __restrict__ maxvio, int* __restrict__ rowtok, int* __restrict__ pairpos) {
  int* sc  = (int*)smemB;           // [256][NE]
  int* sof = (int*)(smemB + 8192);  // [NE]
  int el[16];
  int c[NE];
#pragma unroll
  for (int n = 0; n < NE; n++) c[n] = 0;
#pragma unroll
  for (int i = 0; i < 16; i++) {
    el[i] = topk_idx[tid * 16 + i];
#pragma unroll
    for (int n = 0; n < NE; n++) c[n] += (el[i] == n) ? 1 : 0;
  }
#pragma unroll
  for (int n = 0; n < NE; n++) sc[tid * NE + n] = c[n];
  __syncthreads();
  for (int st = 1; st < 256; st <<= 1) {
    int v[NE];
#pragma unroll
    for (int n = 0; n < NE; n++) v[n] = (tid >= st) ? sc[(tid - st) * NE + n] : 0;
    __syncthreads();
#pragma unroll
    for (int n = 0; n < NE; n++) sc[tid * NE + n] += v[n];
    __syncthreads();
  }
  if (tid == 0) {
    int o = 0, mx = 0;
#pragma unroll
    for (int n = 0; n < NE; n++) {
      int tt = sc[255 * NE + n];
      cnt[n] = tt; offs[n] = o; sof[n] = o;
      o += tt; mx = max(mx, tt);
    }
    maxvio[0] = ((float)mx - 512.f) / 512.f;
  }
  __syncthreads();
  int base[NE];
#pragma unroll
  for (int n = 0; n < NE; n++) base[n] = sof[n] + sc[tid * NE + n] - c[n];
#pragma unroll
  for (int i = 0; i < 16; i++) {
    int eN = el[i];
    int pos = 0;
#pragma unroll
    for (int n = 0; n < NE; n++) if (eN == n) { pos = base[n]; base[n] = pos + 1; }
    rowtok[pos] = (tid * 16 + i) >> 1;
    pairpos[tid * 16 + i] = pos;
  }
}

// gemm1 tile (in-loop fp32 W1 staging) OR W2-transcode for idle tiles. 32 KB LDS.
__device__ __forceinline__ void gemm1_body(int bx, int by, int e, int tid,
    unsigned char* smem,
    const unsigned short* __restrict__ ub, const float* __restrict__ W1,
    const float* __restrict__ b1, const int* __restrict__ rowtok,
    const int* __restrict__ cnts, const int* __restrict__ offs,
    unsigned short* __restrict__ h,
    const float* __restrict__ W2, unsigned short* __restrict__ w2t) {
  int cnt = cnts[e];
  int m0 = by * BM;

  if (m0 >= cnt) {
    int live[NE];
#pragma unroll
    for (int z = 0; z < NE; z++) live[z] = min(16, (cnts[z] + BM - 1) >> 7);
    int rank = 0;
    for (int z = 0; z < e; z++) rank += (16 - live[z]) * 32;
    rank += (by - live[e]) * 32 + bx;
    if (rank >= 2048) return;
    int te = rank >> 8, tt = rank & 255;
    transcode_tile(W2 + (size_t)te * HID * DIMS, w2t + (size_t)te * HID * DIMS,
                   DIMS, HID, (tt & 31) * 128, (tt >> 5) * 128,
                   (unsigned short*)smem, tid);
    return;
  }

  int off = offs[e];
  int n0 = bx * BN;
  int lane = tid & 63;
  int wv = tid >> 6;
  int wm = (tid >> 7) & 1;
  int wn = (tid >> 6) & 1;
  int srow = tid >> 3;
  int cp = tid & 7;
  const float* w1e = W1 + (size_t)e * DIMS * HID;
  const unsigned short* gAp[4];
#pragma unroll
  for (int a = 0; a < 4; a++) {
    int r = a * 32 + srow;
    int c = cp ^ (r & 7);
    int pr = min(off + m0 + r, off + cnt - 1);
    int tok = rowtok[pr];
    gAp[a] = ub + (size_t)tok * DIMS + c * 8;
  }
  int wboff = __builtin_amdgcn_readfirstlane(wv << 10);
  f32x4 acc[4][4];
  f32x4 zz = {0.f, 0.f, 0.f, 0.f};
#pragma unroll
  for (int i = 0; i < 4; i++)
#pragma unroll
    for (int j = 0; j < 4; j++) acc[i][j] = zz;

  int lane15 = lane & 15, quad = lane >> 4, l7 = lane & 7;
  unsigned aRowOff = (unsigned)((wm * 64 + lane15) * 128);
  unsigned bRowOff = (unsigned)(16384 + (wn * 64 + lane15) * 128);

#pragma unroll 1
  for (int k0 = 0; k0 < DIMS; k0 += BK) {
#pragma unroll
    for (int a = 0; a < 4; a++) g2l16(gAp[a] + k0, smem + a * 4096 + wboff);
#pragma unroll
    for (int jj = 0; jj < 4; jj++) {
      int j = wv * 4 + jj;
      int kc = j & 7, nh = j >> 3;
      int nloc = nh * 64 + lane;
      const float* src = w1e + (size_t)(k0 + kc * 8) * HID + n0 + nloc;
      float t0, t1, t2, t3, t4, t5, t6, t7;
      t0 = src[0];               t1 = src[(size_t)HID];
      t2 = src[(size_t)2 * HID]; t3 = src[(size_t)3 * HID];
      t4 = src[(size_t)4 * HID]; t5 = src[(size_t)5 * HID];
      t6 = src[(size_t)6 * HID]; t7 = src[(size_t)7 * HID];
      bf16x8 pk;
      pk[0] = (__bf16)t0; pk[1] = (__bf16)t1; pk[2] = (__bf16)t2; pk[3] = (__bf16)t3;
      pk[4] = (__bf16)t4; pk[5] = (__bf16)t5; pk[6] = (__bf16)t6; pk[7] = (__bf16)t7;
      int cs = kc ^ (lane & 7);
      *(bf16x8*)(smem + 16384 + nloc * 128 + cs * 16) = pk;
    }
    __syncthreads();
#pragma unroll
    for (int s = 0; s < 2; s++) {
      unsigned cpf = (unsigned)(((s * 4 + quad) ^ l7) * 16);
      bf16x8 af[4], bfr[4];
#pragma unroll
      for (int i = 0; i < 4; i++) af[i] = *(const bf16x8*)(smem + aRowOff + i * 2048 + cpf);
#pragma unroll
      for (int j = 0; j < 4; j++) bfr[j] = *(const bf16x8*)(smem + bRowOff + j * 2048 + cpf);
#pragma unroll
      for (int i = 0; i < 4; i++)
#pragma unroll
        for (int j = 0; j < 4; j++)
          acc[i][j] = __builtin_amdgcn_mfma_f32_16x16x32_bf16(af[i], bfr[j], acc[i][j], 0, 0, 0);
    }
    __syncthreads();
  }
  float b1v[4];
#pragma unroll
  for (int j = 0; j < 4; j++) b1v[j] = b1[e * HID + n0 + wn * 64 + j * 16 + lane15];
#pragma unroll
  for (int i = 0; i < 4; i++) {
#pragma unroll
    for (int r = 0; r < 4; r++) {
      int mrow = m0 + wm * 64 + i * 16 + quad * 4 + r;
      if (mrow < cnt) {
        size_t hrow = (size_t)(off + mrow) * HID;
#pragma unroll
        for (int j = 0; j < 4; j++) {
          int col = n0 + wn * 64 + j * 16 + lane15;
          float v = fmaxf(acc[i][j][r] + b1v[j], 0.f);
          h[hrow + col] = f2bf(v);
        }
      }
    }
  }
}

// gemm2 tile from pre-transposed w2t (single-buffered 32 KB, r0-proven)
__device__ __forceinline__ void gemm2_body(int bx, int by, int e, int sp, int tid,
    unsigned char* smem,
    const unsigned short* __restrict__ hbuf, const unsigned short* __restrict__ w2t,
    const float* __restrict__ b2, const int* __restrict__ cnts,
    const int* __restrict__ offs, unsigned short* __restrict__ pout, int KC) {
  int cnt = cnts[e];
  int m0 = by * BM;
  if (m0 >= cnt) return;
  int off = offs[e];
  int n0 = bx * BN;
  int lane = tid & 63;
  int wm = (tid >> 7) & 1;
  int wn = (tid >> 6) & 1;
  int srow = tid >> 3;
  int cp = tid & 7;
  const unsigned short* gA[4];
  const unsigned short* gB[4];
#pragma unroll
  for (int a = 0; a < 4; a++) {
    int r = a * 32 + srow;
    int c = cp ^ (r & 7);
    int pr = min(off + m0 + r, off + cnt - 1);
    gA[a] = hbuf + (size_t)pr * HID + c * 8;
    gB[a] = w2t + ((size_t)e * DIMS + (n0 + r)) * HID + c * 8;
  }
  int wboff = __builtin_amdgcn_readfirstlane((tid >> 6) << 10);
  f32x4 acc[4][4];
  f32x4 zz = {0.f, 0.f, 0.f, 0.f};
#pragma unroll
  for (int i = 0; i < 4; i++)
#pragma unroll
    for (int j = 0; j < 4; j++) acc[i][j] = zz;

  int lane15 = lane & 15, quad = lane >> 4, l7 = lane & 7;
  unsigned aRowOff = (unsigned)((wm * 64 + lane15) * 128);
  unsigned bRowOff = (unsigned)(16384 + (wn * 64 + lane15) * 128);

  int kbeg = sp * KC, kend = kbeg + KC;
#pragma unroll 1
  for (int k0 = kbeg; k0 < kend; k0 += BK) {
#pragma unroll
    for (int a = 0; a < 4; a++) g2l16(gA[a] + k0, smem + a * 4096 + wboff);
#pragma unroll
    for (int a = 0; a < 4; a++) g2l16(gB[a] + k0, smem + 16384 + a * 4096 + wboff);
    __syncthreads();
#pragma unroll
    for (int s = 0; s < 2; s++) {
      unsigned cpf = (unsigned)(((s * 4 + quad) ^ l7) * 16);
      bf16x8 af[4], bfr[4];
#pragma unroll
      for (int i = 0; i < 4; i++) af[i] = *(const bf16x8*)(smem + aRowOff + i * 2048 + cpf);
#pragma unroll
      for (int j = 0; j < 4; j++) bfr[j] = *(const bf16x8*)(smem + bRowOff + j * 2048 + cpf);
#pragma unroll
      for (int i = 0; i < 4; i++)
#pragma unroll
        for (int j = 0; j < 4; j++)
          acc[i][j] = __builtin_amdgcn_mfma_f32_16x16x32_bf16(af[i], bfr[j], acc[i][j], 0, 0, 0);
    }
    __syncthreads();
  }
  float b2v[4];
#pragma unroll
  for (int j = 0; j < 4; j++)
    b2v[j] = (sp == 0) ? b2[e * DIMS + n0 + wn * 64 + j * 16 + lane15] : 0.f;
  unsigned short* pme = pout + (size_t)sp * T_TOK * 2 * DIMS;
#pragma unroll
  for (int i = 0; i < 4; i++) {
#pragma unroll
    for (int r = 0; r < 4; r++) {
      int mrow = m0 + wm * 64 + i * 16 + quad * 4 + r;
      if (mrow < cnt) {
        size_t prow = (size_t)(off + mrow) * DIMS;
#pragma unroll
        for (int j = 0; j < 4; j++) {
          int col = n0 + wn * 64 + j * 16 + lane15;
          pme[prow + col] = f2bf(acc[i][j][r] + b2v[j]);
        }
      }
    }
  }
}

__device__ __forceinline__ void combine_body(int t, int tid,
    const unsigned short* __restrict__ pout, const int* __restrict__ pairpos,
    const float* __restrict__ tkv, float* __restrict__ out, int nsplit) {
  int d = tid * 4;
  int p0 = pairpos[2 * t], p1 = pairpos[2 * t + 1];
  float w0 = tkv[2 * t], w1 = tkv[2 * t + 1];
  float a0 = 0.f, a1 = 0.f, a2 = 0.f, a3 = 0.f;
  float c0 = 0.f, c1 = 0.f, c2 = 0.f, c3 = 0.f;
  const size_t SS = (size_t)T_TOK * 2 * DIMS;
  for (int s = 0; s < nsplit; s++) {
    ushort4 av = *(const ushort4*)(pout + s * SS + (size_t)p0 * DIMS + d);
    ushort4 bv = *(const ushort4*)(pout + s * SS + (size_t)p1 * DIMS + d);
    a0 += bf2f(av.x); a1 += bf2f(av.y); a2 += bf2f(av.z); a3 += bf2f(av.w);
    c0 += bf2f(bv.x); c1 += bf2f(bv.y); c2 += bf2f(bv.z); c3 += bf2f(bv.w);
  }
  float4 o;
  o.x = w0 * a0 + w1 * c0;
  o.y = w0 * a1 + w1 * c1;
  o.z = w0 * a2 + w1 * c2;
  o.w = w0 * a3 + w1 * c3;
  *(float4*)(out + (size_t)t * DIMS + d) = o;
}

// ---------------- mega-kernel: all phases, one cooperative launch ------------
struct MArgs {
  const float *u, *cent, *sbias, *W1, *b1, *W2, *b2;
  unsigned short *ub, *hbuf, *w2t, *pout;
  float *out;
  int *topk_idx; float *topk_val;
  int *cnt, *offs; float *maxvio; int *rowtok, *pairpos;
  int nsplit;
};

__global__ __launch_bounds__(256, 4) void k_mega(MArgs a) {
  __shared__ __align__(16) unsigned char smem[32768];
  int tid = threadIdx.x;
  int bid = (int)blockIdx.x;
  int nb  = (int)gridDim.x;
  cg::grid_group grid = cg::this_grid();

  // P0: routing + u->bf16 cast (one wave per token)
  {
    int wave = tid >> 6, lane = tid & 63;
    for (int t0 = bid * 4; t0 < T_TOK; t0 += nb * 4)
      route_body(t0 + wave, lane, a.u, a.cent, a.sbias, a.topk_idx, a.topk_val, a.ub);
  }
  __threadfence(); grid.sync(); __threadfence();

  // P1: finalize (block 0 only)
  if (bid == 0)
    finalize_body(tid, smem, a.topk_idx, a.cnt, a.offs, a.maxvio, a.rowtok, a.pairpos);
  __threadfence(); grid.sync(); __threadfence();

  // P2: gemm1 compute tiles + W2 transcode in idle tiles (4096 jobs)
  for (int job = bid; job < 4096; job += nb) {
    __syncthreads();
    int e = job >> 9, rem = job & 511;
    gemm1_body(rem & 31, rem >> 5, e, tid, smem,
               a.ub, a.W1, a.b1, a.rowtok, a.cnt, a.offs, a.hbuf, a.W2, a.w2t);
  }
  __threadfence(); grid.sync(); __threadfence();

  // P3: gemm2 (1024 * nsplit jobs)
  {
    int KC = HID / a.nsplit;
    int njob = 1024 * a.nsplit;
    for (int job = bid; job < njob; job += nb) {
      __syncthreads();
      int z = job >> 7, rem = job & 127;
      gemm2_body(rem & 7, rem >> 3, z & 7, z >> 3, tid, smem,
                 a.hbuf, a.w2t, a.b2, a.cnt, a.offs, a.pout, KC);
    }
  }
  __threadfence(); grid.sync(); __threadfence();

  // P4: combine
  for (int t = bid; t < T_TOK; t += nb)
    combine_body(t, tid, a.pout, a.pairpos, a.topk_val, a.out, a.nsplit);
}

// ---------------- fallback wrappers (exact r0 5-kernel sequence) -------------
__global__ __launch_bounds__(256) void k_routeF(const float* u, const float* cent,
    const float* sbias, int* topk_idx, float* topk_val, unsigned short* ub) {
  int wave = threadIdx.x >> 6, lane = threadIdx.x & 63;
  route_body(blockIdx.x * 4 + wave, lane, u, cent, sbias, topk_idx, topk_val, ub);
}

__global__ __launch_bounds__(256) void k_finalF(const int* topk_idx, int* cnt,
    int* offs, float* maxvio, int* rowtok, int* pairpos) {
  __shared__ __align__(16) unsigned char s[8448];
  finalize_body(threadIdx.x, s, topk_idx, cnt, offs, maxvio, rowtok, pairpos);
}

__global__ __launch_bounds__(256) void k_g1F(const unsigned short* ub, const float* W1,
    const float* b1, const int* rowtok, const int* cnts, const int* offs,
    unsigned short* h, const float* W2, unsigned short* w2t) {
  __shared__ __align__(16) unsigned char smem[32768];
  gemm1_body(blockIdx.x, blockIdx.y, blockIdx.z, threadIdx.x, smem,
             ub, W1, b1, rowtok, cnts, offs, h, W2, w2t);
}

__global__ __launch_bounds__(256) void k_g2F(const unsigned short* hbuf,
    const unsigned short* w2t, const float* b2, const int* cnts, const int* offs,
    unsigned short* pout, int KC) {
  __shared__ __align__(16) unsigned char smem[32768];
  int z = blockIdx.z;
  gemm2_body(blockIdx.x, blockIdx.y, z & 7, z >> 3, threadIdx.x, smem,
             hbuf, w2t, b2, cnts, offs, pout, KC);
}

__global__ __launch_bounds__(256) void k_cmbF(const unsigned short* pout,
    const int* pairpos, const float* tkv, float* out, int nsplit) {
  combine_body(blockIdx.x, threadIdx.x, pout, pairpos, tkv, out, nsplit);
}

extern "C" void kernel_launch(void* const* d_in, const int* in_sizes, int n_in,
                              void* d_out, int out_size, void* d_ws, size_t ws_size,
                              hipStream_t stream) {
  const float* u     = (const float*)d_in[0];
  const float* cent  = (const float*)d_in[1];
  const float* sbias = (const float*)d_in[2];
  const float* W1    = (const float*)d_in[3];
  const float* b1    = (const float*)d_in[4];
  const float* W2    = (const float*)d_in[5];
  const float* b2    = (const float*)d_in[6];
  float* out = (float*)d_out;

  char* ws = (char*)d_ws;
  unsigned short* ubuf = (unsigned short*)(ws);                 //  4 MB
  unsigned short* hbuf = (unsigned short*)(ws + 4194304);       // 32 MB
  unsigned short* w2t  = (unsigned short*)(ws + 37748736);      // 64 MB
  const size_t REG4 = 104857600ull;                             // 100 MB mark
  const size_t PSZ = (size_t)T_TOK * 2 * DIMS * 2;              // 8 MB per split

  int nsplit = (ws_size >= REG4 + 4 * PSZ + (1u << 20)) ? 4 : 1;
  unsigned short* poutb = (unsigned short*)(ws + REG4);
  char* r = ws + REG4 + (size_t)nsplit * PSZ;
  int*   cnt      = (int*)(r);
  int*   offs     = (int*)(r + 64);
  int*   topk_idx = (int*)(r + 256);
  float* topk_val = (float*)(r + 256 + 16384);
  int*   rowtok   = (int*)(r + 256 + 32768);
  int*   pairpos  = (int*)(r + 256 + 49152);

  MArgs ma;
  ma.u = u; ma.cent = cent; ma.sbias = sbias; ma.W1 = W1; ma.b1 = b1;
  ma.W2 = W2; ma.b2 = b2;
  ma.ub = ubuf; ma.hbuf = hbuf; ma.w2t = w2t; ma.pout = poutb;
  ma.out = out;
  ma.topk_idx = topk_idx; ma.topk_val = topk_val;
  ma.cnt = cnt; ma.offs = offs; ma.maxvio = out + 2097152;
  ma.rowtok = rowtok; ma.pairpos = pairpos;
  ma.nsplit = nsplit;
  void* kp[] = { &ma };

  hipError_t err = hipLaunchCooperativeKernel((const void*)k_mega, dim3(1024),
                                              dim3(256), kp, 0, stream);
  if (err != hipSuccess) {
    (void)hipGetLastError();
    err = hipLaunchCooperativeKernel((const void*)k_mega, dim3(512),
                                     dim3(256), kp, 0, stream);
  }
  if (err != hipSuccess) {
    (void)hipGetLastError();
    // fallback: proven 5-kernel sequence (r0 structure)
    k_routeF<<<512, 256, 0, stream>>>(u, cent, sbias, topk_idx, topk_val, ubuf);
    k_finalF<<<1, 256, 0, stream>>>(topk_idx, cnt, offs, out + 2097152, rowtok, pairpos);
    k_g1F<<<dim3(32, 16, 8), 256, 0, stream>>>(ubuf, W1, b1, rowtok, cnt, offs, hbuf,
                                               W2, w2t);
    k_g2F<<<dim3(8, 16, 8 * nsplit), 256, 0, stream>>>(hbuf, w2t, b2, cnt, offs,
                                                       poutb, HID / nsplit);
    k_cmbF<<<2048, 256, 0, stream>>>(poutb, pairpos, topk_val, out, nsplit);
  }
}